// Round 2
// baseline (1061710.254 us; speedup 1.0000x reference)
//
#include <hip/hip_runtime.h>
#include <stdint.h>

// Greedy RNN-T decode, persistent cooperative kernel.
// B=64 rows, T=512 frames, 3 symbol steps/frame = 1536 sequential steps.
// Per step: PhaseA (gates GEMM + LSTM -> nh,nc) | bar | PhaseB (jt = tanh(encp + nh@Wd + bj),
// h/c writeback) | bar | PhaseC (logits = jt@Wo + bo, per-WG argmax partials) | bar.
// Argmax finalized redundantly by every WG at the start of the next step (deterministic).
// Output dtype: int32 (reference returns jnp.int32) — harness reads d_out as int32.

#define NB 64
#define NT 512
#define DE 1024
#define EH 640
#define G4 2560
#define NV 4096
#define NSTEP 1536
#define OUTW 1537
#define NWG 256
#define TPB 1024
#define PAD 68   // stride 68 ≡ 4 (mod 32): conflict-free ds_read_b128, 16B-aligned rows

struct KArgs {
  const float* __restrict__ enc;
  const int*   __restrict__ elen;
  const float* __restrict__ embed;
  const float* __restrict__ Wx;
  const float* __restrict__ Wh;
  const float* __restrict__ bl;
  const float* __restrict__ We;
  const float* __restrict__ Wd;
  const float* __restrict__ bj;
  const float* __restrict__ Wo;
  const float* __restrict__ bo;
  int* __restrict__ out;
  int* bar_cnt;
  int* bar_flag;
  float* __restrict__ h_eff;
  float* __restrict__ c_eff;
  float* __restrict__ nh0;
  float* __restrict__ nh1;
  float* __restrict__ nc0;
  float* __restrict__ nc1;
  float* __restrict__ encp;
  float* __restrict__ jt;
  unsigned long long* __restrict__ pmax;
};

__device__ __forceinline__ unsigned int fmono(float f) {
  unsigned int u = __float_as_uint(f);
  return (u & 0x80000000u) ? ~u : (u | 0x80000000u);
}

__device__ __forceinline__ void gbar(int* cnt, int* flag, int epoch) {
  __syncthreads();
  if (threadIdx.x == 0) {
    __threadfence();  // agent-scope release of this XCD's L2 (cross-XCD visibility)
    int prev = __hip_atomic_fetch_add(cnt, 1, __ATOMIC_ACQ_REL, __HIP_MEMORY_SCOPE_AGENT);
    if (prev == NWG - 1) {
      __hip_atomic_store(cnt, 0, __ATOMIC_RELAXED, __HIP_MEMORY_SCOPE_AGENT);
      __hip_atomic_store(flag, epoch, __ATOMIC_RELEASE, __HIP_MEMORY_SCOPE_AGENT);
    } else {
      while (__hip_atomic_load(flag, __ATOMIC_ACQUIRE, __HIP_MEMORY_SCOPE_AGENT) < epoch) {
        __builtin_amdgcn_s_sleep(1);
      }
    }
  }
  __syncthreads();
}

__global__ __launch_bounds__(TPB, 4) void rnnt_fused(KArgs a) {
  const int tid  = threadIdx.x;
  const int wg   = blockIdx.x;
  const int lane = tid & 63;
  const int wvu  = __builtin_amdgcn_readfirstlane(tid >> 6);  // wave id, SGPR

  __shared__ float s_stage[64 * PAD];              // activation tile [64 rows][64 k]
  __shared__ unsigned long long s_red[64 * 17];    // argmax reduce / gate exchange (aliased)
  __shared__ int s_tok[NB];
  __shared__ unsigned char s_eq[NB], s_end[NB];

  float* s_g = (float*)s_red;

  // ragged per-WG LSTM j-slice: 640 j over 256 WGs -> 2 or 3 each
  const int js = (wg * EH) >> 8;
  const int je = ((wg + 1) * EH) >> 8;
  const int nj = je - js;
  const int ncol = 4 * nj;  // gate columns handled by this WG (8 or 12)

  int g_  = wvu / nj;
  int jg_ = wvu - g_ * nj;
  const int mycol = __builtin_amdgcn_readfirstlane(js + jg_ + EH * g_);  // gates col (wvu<ncol)
  const int ccol  = __builtin_amdgcn_readfirstlane(wg * 16 + wvu);       // vocab col
  const int bjcol = __builtin_amdgcn_readfirstlane(js + wvu);            // joint col (wvu<nj)

  for (int s = 0; s <= NSTEP; ++s) {
    const int p = s & 1;
    const float* nh_prev = p ? a.nh0 : a.nh1;
    const float* nc_prev = p ? a.nc0 : a.nc1;
    float* nh_cur = p ? a.nh1 : a.nh0;
    float* nc_cur = p ? a.nc1 : a.nc0;

    // ---- finalize argmax of step s-1: tokens, select mask, end flag, output column s
    if (s > 0) {
      const unsigned long long* pm = a.pmax + (size_t)((s - 1) & 1) * NWG * NB;
      unsigned long long k = 0;
      #pragma unroll
      for (int m = 0; m < 16; ++m) {
        unsigned long long v = pm[(size_t)(wvu + 16 * m) * NB + lane];
        k = v > k ? v : k;
      }
      s_red[lane * 17 + wvu] = k;
      __syncthreads();
      if (tid < NB) {
        unsigned long long kk = 0;
        #pragma unroll
        for (int m = 0; m < 16; ++m) {
          unsigned long long v = s_red[tid * 17 + m];
          kk = v > kk ? v : kk;
        }
        int nt = 4095 - (int)(kk & 0xFFFull);
        int eq = (nt == 0) ? 1 : 0;
        s_eq[tid] = (unsigned char)eq;
        if (!eq) s_tok[tid] = nt;
        int sym = (s - 1) % 3;
        unsigned char e = (sym == 0) ? (unsigned char)eq : (unsigned char)(s_end[tid] | eq);
        s_end[tid] = e;
        if (wg == 0) {
          int fr = (s - 1) / 3;
          int msk = (a.elen[tid] <= fr) || e;
          a.out[(size_t)tid * OUTW + s] = msk ? 0 : nt;
        }
      }
    } else {
      if (tid < NB) {
        s_tok[tid] = 0; s_eq[tid] = 1; s_end[tid] = 0;
        if (wg == 0) a.out[(size_t)tid * OUTW] = 0;
      }
    }
    __syncthreads();
    if (s == NSTEP) break;  // wrote final column 1536; done

    // ================= Phase A =================
    // enc_proj for this frame (computed once per frame, sym 0) for this WG's j-slice
    if (s % 3 == 0) {
      const int fr = s / 3;
      float eacc = 0.0f;
      for (int kt = 0; kt < DE; kt += 64) {
        for (int idx = tid; idx < 64 * 64; idx += TPB) {
          int r = idx >> 6, ki = idx & 63;
          s_stage[r * PAD + ki] = a.enc[((size_t)r * NT + fr) * DE + kt + ki];
        }
        __syncthreads();
        if (wvu < nj) {
          const float* wb = a.We + (size_t)kt * EH + bjcol;
          const float* ap = s_stage + lane * PAD;
          #pragma unroll
          for (int ki = 0; ki < 64; ki += 4) {
            float4 a4 = *(const float4*)(ap + ki);
            eacc = fmaf(a4.x, wb[(size_t)(ki + 0) * EH], eacc);
            eacc = fmaf(a4.y, wb[(size_t)(ki + 1) * EH], eacc);
            eacc = fmaf(a4.z, wb[(size_t)(ki + 2) * EH], eacc);
            eacc = fmaf(a4.w, wb[(size_t)(ki + 3) * EH], eacc);
          }
        }
        __syncthreads();
      }
      if (wvu < nj) a.encp[lane * EH + bjcol] = eacc;
    }

    // gates = [emb | h] @ [Wx ; Wh] for this WG's 4*nj columns; K = 1280
    {
      float acc = 0.0f;
      for (int kt = 0; kt < 2 * EH; kt += 64) {
        for (int idx = tid; idx < 64 * 64; idx += TPB) {
          int r = idx >> 6, ki = idx & 63, k = kt + ki;
          float v;
          if (k < EH) {
            v = a.embed[(size_t)s_tok[r] * EH + k];
          } else {
            const float* hp = s_eq[r] ? a.h_eff : nh_prev;
            v = hp[r * EH + (k - EH)];
          }
          s_stage[r * PAD + ki] = v;
        }
        __syncthreads();
        if (wvu < ncol) {
          const float* wb = (kt < EH ? a.Wx + (size_t)kt * G4
                                     : a.Wh + (size_t)(kt - EH) * G4) + mycol;
          const float* ap = s_stage + lane * PAD;
          #pragma unroll
          for (int ki = 0; ki < 64; ki += 4) {
            float4 a4 = *(const float4*)(ap + ki);
            acc = fmaf(a4.x, wb[(size_t)(ki + 0) * G4], acc);
            acc = fmaf(a4.y, wb[(size_t)(ki + 1) * G4], acc);
            acc = fmaf(a4.z, wb[(size_t)(ki + 2) * G4], acc);
            acc = fmaf(a4.w, wb[(size_t)(ki + 3) * G4], acc);
          }
        }
        __syncthreads();
      }
      if (wvu < ncol) s_g[lane * 17 + wvu] = acc + a.bl[mycol];
      __syncthreads();
      // LSTM elementwise on this WG's j-slice
      if (wvu < nj) {
        int j = js + wvu;
        float gi = s_g[lane * 17 + (0 * nj + wvu)];
        float gf = s_g[lane * 17 + (1 * nj + wvu)];
        float gg = s_g[lane * 17 + (2 * nj + wvu)];
        float go = s_g[lane * 17 + (3 * nj + wvu)];
        float cp = s_eq[lane] ? a.c_eff[lane * EH + j] : nc_prev[lane * EH + j];
        float si = 1.0f / (1.0f + expf(-gi));
        float sf = 1.0f / (1.0f + expf(-gf));
        float so = 1.0f / (1.0f + expf(-go));
        float ncv = sf * cp + si * tanhf(gg);
        float nhv = so * tanhf(ncv);
        nh_cur[lane * EH + j] = nhv;
        nc_cur[lane * EH + j] = ncv;
      }
    }
    gbar(a.bar_cnt, a.bar_flag, 3 * s + 1);

    // ================= Phase B =================
    // lagged h/c writeback: h_eff <- select(eq_{s-1}, h_eff, nh_{s-1})  (disjoint slices)
    if (tid < 320) {
      int fid = wg * 320 + tid;
      int isC = fid >= NB * EH;
      int e = isC ? fid - NB * EH : fid;
      int r = e / EH;
      if (!s_eq[r]) {
        if (isC) a.c_eff[e] = nc_prev[e];
        else     a.h_eff[e] = nh_prev[e];
      }
    }
    // jt = tanh(encp + nh_s @ Wd + bj) for this WG's j-slice; K = 640
    {
      float bacc = 0.0f;
      for (int kt = 0; kt < EH; kt += 64) {
        for (int idx = tid; idx < 64 * 64; idx += TPB) {
          int r = idx >> 6, ki = idx & 63;
          s_stage[r * PAD + ki] = nh_cur[r * EH + kt + ki];
        }
        __syncthreads();
        if (wvu < nj) {
          const float* wb = a.Wd + (size_t)kt * EH + bjcol;
          const float* ap = s_stage + lane * PAD;
          #pragma unroll
          for (int ki = 0; ki < 64; ki += 4) {
            float4 a4 = *(const float4*)(ap + ki);
            bacc = fmaf(a4.x, wb[(size_t)(ki + 0) * EH], bacc);
            bacc = fmaf(a4.y, wb[(size_t)(ki + 1) * EH], bacc);
            bacc = fmaf(a4.z, wb[(size_t)(ki + 2) * EH], bacc);
            bacc = fmaf(a4.w, wb[(size_t)(ki + 3) * EH], bacc);
          }
        }
        __syncthreads();
      }
      if (wvu < nj) {
        float jd = bacc + a.encp[lane * EH + bjcol] + a.bj[bjcol];
        a.jt[lane * EH + bjcol] = tanhf(jd);
      }
    }
    gbar(a.bar_cnt, a.bar_flag, 3 * s + 2);

    // ================= Phase C =================
    // logits tile [64 rows x 16 vocab cols], wave-per-column; per-WG argmax partial
    {
      float cacc = 0.0f;
      for (int kt = 0; kt < EH; kt += 64) {
        for (int idx = tid; idx < 64 * 64; idx += TPB) {
          int r = idx >> 6, ki = idx & 63;
          s_stage[r * PAD + ki] = a.jt[r * EH + kt + ki];
        }
        __syncthreads();
        {
          const float* wb = a.Wo + (size_t)kt * NV + ccol;
          const float* ap = s_stage + lane * PAD;
          #pragma unroll
          for (int ki = 0; ki < 64; ki += 4) {
            float4 a4 = *(const float4*)(ap + ki);
            cacc = fmaf(a4.x, wb[(size_t)(ki + 0) * NV], cacc);
            cacc = fmaf(a4.y, wb[(size_t)(ki + 1) * NV], cacc);
            cacc = fmaf(a4.z, wb[(size_t)(ki + 2) * NV], cacc);
            cacc = fmaf(a4.w, wb[(size_t)(ki + 3) * NV], cacc);
          }
        }
        __syncthreads();
      }
      cacc += a.bo[ccol];
      // pack: monotonic(float) in high bits, (4095 - col) low 12 bits -> first-index tie-break
      unsigned long long key =
          ((unsigned long long)fmono(cacc) << 12) | (unsigned long long)(4095 - ccol);
      s_red[lane * 17 + wvu] = key;
      __syncthreads();
      if (tid < NB) {
        unsigned long long kk = 0;
        #pragma unroll
        for (int m = 0; m < 16; ++m) {
          unsigned long long v = s_red[tid * 17 + m];
          kk = v > kk ? v : kk;
        }
        a.pmax[(size_t)p * NWG * NB + (size_t)wg * NB + tid] = kk;
      }
    }
    gbar(a.bar_cnt, a.bar_flag, 3 * s + 3);
  }
}

extern "C" void kernel_launch(void* const* d_in, const int* in_sizes, int n_in,
                              void* d_out, int out_size, void* d_ws, size_t ws_size,
                              hipStream_t stream) {
  KArgs a;
  a.enc   = (const float*)d_in[0];
  a.elen  = (const int*)  d_in[1];
  a.embed = (const float*)d_in[2];
  a.Wx    = (const float*)d_in[3];
  a.Wh    = (const float*)d_in[4];
  a.bl    = (const float*)d_in[5];
  a.We    = (const float*)d_in[6];
  a.Wd    = (const float*)d_in[7];
  a.bj    = (const float*)d_in[8];
  a.Wo    = (const float*)d_in[9];
  a.bo    = (const float*)d_in[10];
  a.out   = (int*)d_out;

  char* w = (char*)d_ws;
  size_t off = 0;
  auto alloc = [&](size_t bytes) -> char* {
    char* pp = w + off;
    off += (bytes + 255) & ~(size_t)255;
    return pp;
  };
  a.bar_cnt  = (int*)alloc(4);
  a.bar_flag = (int*)alloc(4);
  a.h_eff = (float*)alloc((size_t)NB * EH * 4);
  a.c_eff = (float*)alloc((size_t)NB * EH * 4);
  size_t zero_bytes = off;  // barrier + h_eff + c_eff must start at 0
  a.nh0  = (float*)alloc((size_t)NB * EH * 4);
  a.nh1  = (float*)alloc((size_t)NB * EH * 4);
  a.nc0  = (float*)alloc((size_t)NB * EH * 4);
  a.nc1  = (float*)alloc((size_t)NB * EH * 4);
  a.encp = (float*)alloc((size_t)NB * EH * 4);
  a.jt   = (float*)alloc((size_t)NB * EH * 4);
  a.pmax = (unsigned long long*)alloc((size_t)2 * NWG * NB * 8);

  hipMemsetAsync(d_ws, 0, zero_bytes, stream);
  void* params[] = { &a };
  hipLaunchCooperativeKernel((const void*)rnnt_fused, dim3(NWG), dim3(TPB),
                             params, 0, stream);
}

// Round 3
// 353229.297 us; speedup vs baseline: 3.0057x; 3.0057x over previous
//
#include <hip/hip_runtime.h>
#include <stdint.h>

// Greedy RNN-T decode, persistent cooperative kernel, coalesced-weight GEMMs.
// B=64, T=512, 3 sym/frame = 1536 sequential steps; 3 grid barriers/step.
// Per step:
//  I1: gates=[emb|h]@[Wx;Wh]+LSTM (WGs 0..79) | encp=enc@We at frame start (80..119)
//      | lagged h/c writeback (120..135)
//  I2: jt = tanh(encp + nh@Wd + bj)           (WGs 0..39)
//  I3: logits = jt@Wo + bo, per-WG argmax partials -> pmax  (WGs 0..127)
// Finalize (all WGs, redundant, deterministic) at start of next step.
// GEMM structure: lanes span output cols (coalesced dwordx2/x4 weight loads),
// activations staged in LDS read as wave-uniform float4 broadcast, K split
// over 16 waves, LDS atomicAdd reduction.

#define NB 64
#define NT 512
#define DE 1024
#define EH 640
#define G4 2560
#define NV 4096
#define NSTEP 1536
#define OUTW 1537
#define NWG 136
#define TPB 1024

struct KArgs {
  const float* __restrict__ enc;
  const int*   __restrict__ elen;
  const float* __restrict__ embed;
  const float* __restrict__ Wx;
  const float* __restrict__ Wh;
  const float* __restrict__ bl;
  const float* __restrict__ We;
  const float* __restrict__ Wd;
  const float* __restrict__ bj;
  const float* __restrict__ Wo;
  const float* __restrict__ bo;
  int* __restrict__ out;
  int* bar_cnt;
  int* bar_flag;
  float* __restrict__ h_eff;
  float* __restrict__ c_eff;
  float* __restrict__ nh0;
  float* __restrict__ nh1;
  float* __restrict__ nc0;
  float* __restrict__ nc1;
  float* __restrict__ encp;
  float* __restrict__ jt;
  unsigned long long* __restrict__ pmax;   // [64 rows][16 colblocks]
};

__device__ __forceinline__ unsigned int fmono(float f) {
  unsigned int u = __float_as_uint(f);
  return (u & 0x80000000u) ? ~u : (u | 0x80000000u);
}

__device__ __forceinline__ void gbar(int* cnt, int* flag, int epoch) {
  __syncthreads();
  if (threadIdx.x == 0) {
    __threadfence();
    int prev = __hip_atomic_fetch_add(cnt, 1, __ATOMIC_ACQ_REL, __HIP_MEMORY_SCOPE_AGENT);
    if (prev == NWG - 1) {
      __hip_atomic_store(cnt, 0, __ATOMIC_RELAXED, __HIP_MEMORY_SCOPE_AGENT);
      __hip_atomic_store(flag, epoch, __ATOMIC_RELEASE, __HIP_MEMORY_SCOPE_AGENT);
    } else {
      while (__hip_atomic_load(flag, __ATOMIC_ACQUIRE, __HIP_MEMORY_SCOPE_AGENT) < epoch) {
        __builtin_amdgcn_s_sleep(1);
      }
    }
  }
  __syncthreads();
}

// 16 FMAs: acc(float4, 4 cols) += xa(float4, 4 k's) * w0..w3(float4 weight rows)
#define FMA4x4(accr, xa, w0, w1, w2, w3)            \
  accr.x = fmaf(xa.x, w0.x, accr.x);                \
  accr.y = fmaf(xa.x, w0.y, accr.y);                \
  accr.z = fmaf(xa.x, w0.z, accr.z);                \
  accr.w = fmaf(xa.x, w0.w, accr.w);                \
  accr.x = fmaf(xa.y, w1.x, accr.x);                \
  accr.y = fmaf(xa.y, w1.y, accr.y);                \
  accr.z = fmaf(xa.y, w1.z, accr.z);                \
  accr.w = fmaf(xa.y, w1.w, accr.w);                \
  accr.x = fmaf(xa.z, w2.x, accr.x);                \
  accr.y = fmaf(xa.z, w2.y, accr.y);                \
  accr.z = fmaf(xa.z, w2.z, accr.z);                \
  accr.w = fmaf(xa.z, w2.w, accr.w);                \
  accr.x = fmaf(xa.w, w3.x, accr.x);                \
  accr.y = fmaf(xa.w, w3.y, accr.y);                \
  accr.w = fmaf(xa.w, w3.w, accr.w);                \
  accr.z = fmaf(xa.w, w3.z, accr.z);

// 8 FMAs: acc(float2, 2 cols) += xa(float4) * w0..w3(float2)
#define FMA4x2(accr, xa, w0, w1, w2, w3)            \
  accr.x = fmaf(xa.x, w0.x, accr.x);                \
  accr.y = fmaf(xa.x, w0.y, accr.y);                \
  accr.x = fmaf(xa.y, w1.x, accr.x);                \
  accr.y = fmaf(xa.y, w1.y, accr.y);                \
  accr.x = fmaf(xa.z, w2.x, accr.x);                \
  accr.y = fmaf(xa.z, w2.y, accr.y);                \
  accr.x = fmaf(xa.w, w3.x, accr.x);                \
  accr.y = fmaf(xa.w, w3.y, accr.y);

__global__ __launch_bounds__(TPB, 4) void rnnt_fused(KArgs a) {
  const int tid  = threadIdx.x;
  const int bid  = blockIdx.x;
  const int lane = tid & 63;
  const int wv   = __builtin_amdgcn_readfirstlane(tid >> 6);  // wave id 0..15

  __shared__ __align__(16) float s_X[8 * 1280];     // activation rows [8][K<=1280]
  __shared__ float s_acc[8 * 256];                  // reduction buffer [8 r][<=256 c]
  __shared__ unsigned long long s_red[1152];        // argmax scratch
  __shared__ int s_tok[NB];
  __shared__ unsigned char s_eq[NB], s_end[NB];

  for (int s = 0; s <= NSTEP; ++s) {
    const int p = s & 1;
    const float* nh_prev = p ? a.nh0 : a.nh1;
    const float* nc_prev = p ? a.nc0 : a.nc1;
    float* nh_cur = p ? a.nh1 : a.nh0;
    float* nc_cur = p ? a.nc1 : a.nc0;

    // ---------- finalize argmax of step s-1 (redundant per WG) ----------
    if (bid < 80 || bid >= 120) {   // E-only WGs never consume tok/eq/end
      if (s > 0) {
        { int r = tid >> 4, cb = tid & 15;
          s_red[r * 17 + cb] = a.pmax[r * 16 + cb]; }
        __syncthreads();
        if (tid < NB) {
          unsigned long long kk = 0;
          #pragma unroll
          for (int m = 0; m < 16; ++m) {
            unsigned long long v = s_red[tid * 17 + m];
            kk = v > kk ? v : kk;
          }
          int nt = 4095 - (int)(kk & 0xFFFull);
          int eq = (nt == 0) ? 1 : 0;
          s_eq[tid] = (unsigned char)eq;
          if (!eq) s_tok[tid] = nt;
          int sym = (s - 1) % 3;
          unsigned char e = (sym == 0) ? (unsigned char)eq : (unsigned char)(s_end[tid] | eq);
          s_end[tid] = e;
          if (bid == 0) {
            int fr = (s - 1) / 3;
            int msk = (a.elen[tid] <= fr) || e;
            a.out[(size_t)tid * OUTW + s] = msk ? 0 : nt;
          }
        }
      } else {
        if (tid < NB) {
          s_tok[tid] = 0; s_eq[tid] = 1; s_end[tid] = 0;
          if (bid == 0) a.out[(size_t)tid * OUTW] = 0;
        }
      }
    }
    __syncthreads();
    if (s == NSTEP) break;

    // =================== Interval 1 ===================
    if (bid < 80) {
      // gates GEMM: rows r0..r0+7, cols = 4 gates x 64 j's (jb), K=1280 over 16 waves
      const int jb = bid >> 3, rb = bid & 7;
      const int j0 = jb * 64, r0 = rb * 8;
      for (int i = tid; i < 8 * 256; i += TPB) s_acc[i] = 0.0f;
      #pragma unroll
      for (int r = 0; r < 8; ++r) {
        const int rg = r0 + r;
        const float* se = a.embed + (size_t)s_tok[rg] * EH;
        const float* sh = (s_eq[rg] ? a.h_eff : nh_prev) + (size_t)rg * EH;
        for (int k = tid; k < 1280; k += TPB)
          s_X[r * 1280 + k] = (k < 640) ? se[k] : sh[k - 640];
      }
      __syncthreads();
      {
        const int k0 = (wv & 7) * 80;
        const int kbase = k0 + ((wv < 8) ? 0 : 640);
        const int colb = (lane >> 4) * EH + j0 + 4 * (lane & 15);
        const float* wp = ((wv < 8) ? a.Wx : a.Wh) + (size_t)k0 * G4 + colb;
        float4 acc[8];
        #pragma unroll
        for (int r = 0; r < 8; ++r) acc[r] = float4{0.f, 0.f, 0.f, 0.f};
        for (int kk = 0; kk < 80; kk += 4) {
          float4 w0 = *(const float4*)(wp);
          float4 w1 = *(const float4*)(wp + G4);
          float4 w2 = *(const float4*)(wp + 2 * G4);
          float4 w3 = *(const float4*)(wp + 3 * G4);
          wp += 4 * (size_t)G4;
          #pragma unroll
          for (int r = 0; r < 8; ++r) {
            float4 xa = *(const float4*)(s_X + r * 1280 + kbase + kk);
            FMA4x4(acc[r], xa, w0, w1, w2, w3)
          }
        }
        const int cl = (lane >> 4) * 64 + 4 * (lane & 15);
        #pragma unroll
        for (int r = 0; r < 8; ++r) {
          atomicAdd(&s_acc[r * 256 + cl + 0], acc[r].x);
          atomicAdd(&s_acc[r * 256 + cl + 1], acc[r].y);
          atomicAdd(&s_acc[r * 256 + cl + 2], acc[r].z);
          atomicAdd(&s_acc[r * 256 + cl + 3], acc[r].w);
        }
      }
      __syncthreads();
      if (tid < 512) {   // LSTM elementwise: 8 rows x 64 j
        const int r = tid >> 6, jl = tid & 63;
        const int rg = r0 + r, j = j0 + jl;
        float gi = s_acc[r * 256 +   0 + jl] + a.bl[j];
        float gf = s_acc[r * 256 +  64 + jl] + a.bl[EH + j];
        float gg = s_acc[r * 256 + 128 + jl] + a.bl[2 * EH + j];
        float go = s_acc[r * 256 + 192 + jl] + a.bl[3 * EH + j];
        float cp = s_eq[rg] ? a.c_eff[(size_t)rg * EH + j] : nc_prev[(size_t)rg * EH + j];
        float si = 1.0f / (1.0f + expf(-gi));
        float sf = 1.0f / (1.0f + expf(-gf));
        float so = 1.0f / (1.0f + expf(-go));
        float ncv = sf * cp + si * tanhf(gg);
        float nhv = so * tanhf(ncv);
        nh_cur[(size_t)rg * EH + j] = nhv;
        nc_cur[(size_t)rg * EH + j] = ncv;
      }
    } else if (bid < 120) {
      if (s % 3 == 0) {
        // encp = enc_t @ We: rows 8, cols 128, K=1024 over 16 waves
        const int eb = bid - 80;
        const int cb = eb >> 3, rb = eb & 7;
        const int c0 = cb * 128, r0 = rb * 8;
        const int fr = s / 3;
        for (int i = tid; i < 8 * 128; i += TPB) s_acc[i] = 0.0f;
        #pragma unroll
        for (int r = 0; r < 8; ++r) {
          const float* sp = a.enc + ((size_t)(r0 + r) * NT + fr) * DE;
          for (int k = tid; k < 1024; k += TPB) s_X[r * 1024 + k] = sp[k];
        }
        __syncthreads();
        {
          const int k0 = wv * 64;
          const int colb = c0 + 2 * lane;
          const float* wp = a.We + (size_t)k0 * EH + colb;
          float2 acc[8];
          #pragma unroll
          for (int r = 0; r < 8; ++r) acc[r] = float2{0.f, 0.f};
          for (int kk = 0; kk < 64; kk += 4) {
            float2 w0 = *(const float2*)(wp);
            float2 w1 = *(const float2*)(wp + EH);
            float2 w2 = *(const float2*)(wp + 2 * EH);
            float2 w3 = *(const float2*)(wp + 3 * EH);
            wp += 4 * (size_t)EH;
            #pragma unroll
            for (int r = 0; r < 8; ++r) {
              float4 xa = *(const float4*)(s_X + r * 1024 + k0 + kk);
              FMA4x2(acc[r], xa, w0, w1, w2, w3)
            }
          }
          const int cl = 2 * lane;
          #pragma unroll
          for (int r = 0; r < 8; ++r) {
            atomicAdd(&s_acc[r * 128 + cl + 0], acc[r].x);
            atomicAdd(&s_acc[r * 128 + cl + 1], acc[r].y);
          }
        }
        __syncthreads();
        { const int r = tid >> 7, c = tid & 127;
          a.encp[(size_t)(r0 + r) * EH + c0 + c] = s_acc[r * 128 + c]; }
      }
    } else {
      // lagged h/c writeback: h_eff <- nh_prev where !eq (disjoint from A's reads)
      const int base = (bid - 120) * 5120;
      #pragma unroll
      for (int i = 0; i < 5; ++i) {
        int e = base + i * TPB + tid;            // < 2*NB*EH = 81920
        int isC = e >= NB * EH;
        int e2 = isC ? e - NB * EH : e;
        int r = e2 / EH;
        if (!s_eq[r]) {
          if (isC) a.c_eff[e2] = nc_prev[e2];
          else     a.h_eff[e2] = nh_prev[e2];
        }
      }
    }
    gbar(a.bar_cnt, a.bar_flag, 3 * s + 1);

    // =================== Interval 2 ===================
    if (bid < 40) {
      // jt = tanh(encp + nh @ Wd + bj): rows 8, cols 128, K=640 over 16 waves
      const int cb = bid >> 3, rb = bid & 7;
      const int c0 = cb * 128, r0 = rb * 8;
      for (int i = tid; i < 8 * 128; i += TPB) s_acc[i] = 0.0f;
      #pragma unroll
      for (int r = 0; r < 8; ++r) {
        const float* sp = nh_cur + (size_t)(r0 + r) * EH;
        for (int k = tid; k < 640; k += TPB) s_X[r * 640 + k] = sp[k];
      }
      __syncthreads();
      {
        const int k0 = wv * 40;
        const int colb = c0 + 2 * lane;
        const float* wp = a.Wd + (size_t)k0 * EH + colb;
        float2 acc[8];
        #pragma unroll
        for (int r = 0; r < 8; ++r) acc[r] = float2{0.f, 0.f};
        for (int kk = 0; kk < 40; kk += 4) {
          float2 w0 = *(const float2*)(wp);
          float2 w1 = *(const float2*)(wp + EH);
          float2 w2 = *(const float2*)(wp + 2 * EH);
          float2 w3 = *(const float2*)(wp + 3 * EH);
          wp += 4 * (size_t)EH;
          #pragma unroll
          for (int r = 0; r < 8; ++r) {
            float4 xa = *(const float4*)(s_X + r * 640 + k0 + kk);
            FMA4x2(acc[r], xa, w0, w1, w2, w3)
          }
        }
        const int cl = 2 * lane;
        #pragma unroll
        for (int r = 0; r < 8; ++r) {
          atomicAdd(&s_acc[r * 128 + cl + 0], acc[r].x);
          atomicAdd(&s_acc[r * 128 + cl + 1], acc[r].y);
        }
      }
      __syncthreads();
      { const int r = tid >> 7, c = tid & 127;
        const int rg = r0 + r, cg = c0 + c;
        float v = s_acc[r * 128 + c] + a.encp[(size_t)rg * EH + cg] + a.bj[cg];
        a.jt[(size_t)rg * EH + cg] = tanhf(v); }
    }
    gbar(a.bar_cnt, a.bar_flag, 3 * s + 2);

    // =================== Interval 3 ===================
    if (bid < 128) {
      // logits tile: rows 8, cols 256, K=640 over 16 waves; argmax partial
      const int cb = bid >> 3, rb = bid & 7;
      const int c0 = cb * 256, r0 = rb * 8;
      for (int i = tid; i < 8 * 256; i += TPB) s_acc[i] = 0.0f;
      #pragma unroll
      for (int r = 0; r < 8; ++r) {
        const float* sp = a.jt + (size_t)(r0 + r) * EH;
        for (int k = tid; k < 640; k += TPB) s_X[r * 640 + k] = sp[k];
      }
      __syncthreads();
      {
        const int k0 = wv * 40;
        const int colb = c0 + 4 * lane;
        const float* wp = a.Wo + (size_t)k0 * NV + colb;
        float4 acc[8];
        #pragma unroll
        for (int r = 0; r < 8; ++r) acc[r] = float4{0.f, 0.f, 0.f, 0.f};
        for (int kk = 0; kk < 40; kk += 4) {
          float4 w0 = *(const float4*)(wp);
          float4 w1 = *(const float4*)(wp + NV);
          float4 w2 = *(const float4*)(wp + 2 * NV);
          float4 w3 = *(const float4*)(wp + 3 * NV);
          wp += 4 * (size_t)NV;
          #pragma unroll
          for (int r = 0; r < 8; ++r) {
            float4 xa = *(const float4*)(s_X + r * 640 + k0 + kk);
            FMA4x4(acc[r], xa, w0, w1, w2, w3)
          }
        }
        const int cl = 4 * lane;
        #pragma unroll
        for (int r = 0; r < 8; ++r) {
          atomicAdd(&s_acc[r * 256 + cl + 0], acc[r].x);
          atomicAdd(&s_acc[r * 256 + cl + 1], acc[r].y);
          atomicAdd(&s_acc[r * 256 + cl + 2], acc[r].z);
          atomicAdd(&s_acc[r * 256 + cl + 3], acc[r].w);
        }
      }
      __syncthreads();
      { const int r = tid >> 7, m = tid & 127;
        float v0 = s_acc[r * 256 + 2 * m]     + a.bo[c0 + 2 * m];
        float v1 = s_acc[r * 256 + 2 * m + 1] + a.bo[c0 + 2 * m + 1];
        unsigned long long k0 =
            ((unsigned long long)fmono(v0) << 12) | (unsigned long long)(4095 - (c0 + 2 * m));
        unsigned long long k1 =
            ((unsigned long long)fmono(v1) << 12) | (unsigned long long)(4095 - (c0 + 2 * m + 1));
        s_red[r * 144 + m] = k0 > k1 ? k0 : k1; }
      __syncthreads();
      if (tid < 128) {
        const int r = tid >> 4, m = tid & 15;
        unsigned long long kk = 0;
        #pragma unroll
        for (int i = 0; i < 8; ++i) {
          unsigned long long v = s_red[r * 144 + m * 8 + i];
          kk = v > kk ? v : kk;
        }
        s_red[r * 144 + 128 + m] = kk;
      }
      __syncthreads();
      if (tid < 8) {
        unsigned long long kk = 0;
        #pragma unroll
        for (int i = 0; i < 16; ++i) {
          unsigned long long v = s_red[tid * 144 + 128 + i];
          kk = v > kk ? v : kk;
        }
        a.pmax[(size_t)(r0 + tid) * 16 + cb] = kk;
      }
    }
    gbar(a.bar_cnt, a.bar_flag, 3 * s + 3);
  }
}

extern "C" void kernel_launch(void* const* d_in, const int* in_sizes, int n_in,
                              void* d_out, int out_size, void* d_ws, size_t ws_size,
                              hipStream_t stream) {
  KArgs a;
  a.enc   = (const float*)d_in[0];
  a.elen  = (const int*)  d_in[1];
  a.embed = (const float*)d_in[2];
  a.Wx    = (const float*)d_in[3];
  a.Wh    = (const float*)d_in[4];
  a.bl    = (const float*)d_in[5];
  a.We    = (const float*)d_in[6];
  a.Wd    = (const float*)d_in[7];
  a.bj    = (const float*)d_in[8];
  a.Wo    = (const float*)d_in[9];
  a.bo    = (const float*)d_in[10];
  a.out   = (int*)d_out;

  char* w = (char*)d_ws;
  size_t off = 0;
  auto alloc = [&](size_t bytes) -> char* {
    char* pp = w + off;
    off += (bytes + 255) & ~(size_t)255;
    return pp;
  };
  a.bar_cnt  = (int*)alloc(4);
  a.bar_flag = (int*)alloc(4);
  a.h_eff = (float*)alloc((size_t)NB * EH * 4);
  a.c_eff = (float*)alloc((size_t)NB * EH * 4);
  size_t zero_bytes = off;  // barrier + h_eff + c_eff must start at 0
  a.nh0  = (float*)alloc((size_t)NB * EH * 4);
  a.nh1  = (float*)alloc((size_t)NB * EH * 4);
  a.nc0  = (float*)alloc((size_t)NB * EH * 4);
  a.nc1  = (float*)alloc((size_t)NB * EH * 4);
  a.encp = (float*)alloc((size_t)NB * EH * 4);
  a.jt   = (float*)alloc((size_t)NB * EH * 4);
  a.pmax = (unsigned long long*)alloc((size_t)NB * 16 * 8);

  hipMemsetAsync(d_ws, 0, zero_bytes, stream);
  void* params[] = { &a };
  hipLaunchCooperativeKernel((const void*)rnnt_fused, dim3(NWG), dim3(TPB),
                             params, 0, stream);
}

// Round 4
// 345772.095 us; speedup vs baseline: 3.0705x; 1.0216x over previous
//
#include <hip/hip_runtime.h>
#include <stdint.h>

// Greedy RNN-T decode, persistent cooperative kernel, v3.
// Changes vs v2: (1) GEMMs restructured to 32-row x 64-col tiles per WG
// (x2 weight-read redundancy instead of x8), K split over 16 waves, X staged
// in LDS K-chunks (double-buffered); (2) barrier uses relaxed scoped atomics
// + one release/acquire fence per WG (no per-poll L2 invalidate) and a
// two-level counter tree; (3) 1-deep weight prefetch in the inner loop.

#define NB 64
#define NT 512
#define DE 1024
#define EH 640
#define G4 2560
#define NV 4096
#define NSTEP 1536
#define OUTW 1537
#define NWG 128
#define TPB 1024

#define XS_G 324          // gates chunk stride (320+4): 324 % 32 == 4
#define XS_E 260          // encp chunk stride (256+4)
#define XS_F 644          // flat stride (640+4)
#define XHALF (32 * 324)  // floats per double-buffer half

struct KArgs {
  const float* __restrict__ enc;
  const int*   __restrict__ elen;
  const float* __restrict__ embed;
  const float* __restrict__ Wx;
  const float* __restrict__ Wh;
  const float* __restrict__ bl;
  const float* __restrict__ We;
  const float* __restrict__ Wd;
  const float* __restrict__ bj;
  const float* __restrict__ Wo;
  const float* __restrict__ bo;
  int* __restrict__ out;
  int* bar;                       // [0..255] sub cnts (8 x stride 32), [256] master, [288] flag
  float* __restrict__ h_eff;
  float* __restrict__ c_eff;
  float* __restrict__ nh0;
  float* __restrict__ nh1;
  float* __restrict__ nc0;
  float* __restrict__ nc1;
  float* __restrict__ encp;
  float* __restrict__ jt;
  unsigned long long* __restrict__ pmax;   // [64 rows][64 colblocks]
};

__device__ __forceinline__ unsigned int fmono(float f) {
  unsigned int u = __float_as_uint(f);
  return (u & 0x80000000u) ? ~u : (u | 0x80000000u);
}

// Two-level grid barrier. One release fence (L2 wb) + one acquire fence
// (L2 inv) per WG per barrier; poll is a RELAXED scoped load (no inv).
__device__ __forceinline__ void gbar(int* bar, int epoch, int bid) {
  __syncthreads();
  if (threadIdx.x == 0) {
    __builtin_amdgcn_fence(__ATOMIC_RELEASE, "agent");
    int g = bid & 7;
    int prev = __hip_atomic_fetch_add(&bar[g * 32], 1, __ATOMIC_RELAXED,
                                      __HIP_MEMORY_SCOPE_AGENT);
    if (prev == 15) {
      __hip_atomic_store(&bar[g * 32], 0, __ATOMIC_RELAXED, __HIP_MEMORY_SCOPE_AGENT);
      int pm = __hip_atomic_fetch_add(&bar[256], 1, __ATOMIC_RELAXED,
                                      __HIP_MEMORY_SCOPE_AGENT);
      if (pm == 7) {
        __hip_atomic_store(&bar[256], 0, __ATOMIC_RELAXED, __HIP_MEMORY_SCOPE_AGENT);
        __hip_atomic_store(&bar[288], epoch, __ATOMIC_RELEASE, __HIP_MEMORY_SCOPE_AGENT);
      }
    }
    while (__hip_atomic_load(&bar[288], __ATOMIC_RELAXED, __HIP_MEMORY_SCOPE_AGENT) < epoch)
      __builtin_amdgcn_s_sleep(1);
    __builtin_amdgcn_fence(__ATOMIC_ACQUIRE, "agent");
  }
  __syncthreads();
}

#define FMA16(A, xa, w0, w1, w2, w3)                          \
  A.x = fmaf(xa.x, w0.x, A.x); A.y = fmaf(xa.x, w0.y, A.y);   \
  A.z = fmaf(xa.x, w0.z, A.z); A.w = fmaf(xa.x, w0.w, A.w);   \
  A.x = fmaf(xa.y, w1.x, A.x); A.y = fmaf(xa.y, w1.y, A.y);   \
  A.z = fmaf(xa.y, w1.z, A.z); A.w = fmaf(xa.y, w1.w, A.w);   \
  A.x = fmaf(xa.z, w2.x, A.x); A.y = fmaf(xa.z, w2.y, A.y);   \
  A.z = fmaf(xa.z, w2.z, A.z); A.w = fmaf(xa.z, w2.w, A.w);   \
  A.x = fmaf(xa.w, w3.x, A.x); A.y = fmaf(xa.w, w3.y, A.y);   \
  A.z = fmaf(xa.w, w3.z, A.z); A.w = fmaf(xa.w, w3.w, A.w);

// K-slice of a 32rows x 64cols tile. wp: weights at (k0, lane's 4 cols);
// xb: LDS X at (rowgroup rg, k0). 1-deep weight prefetch.
__device__ __forceinline__ void gemm_ks(const float* __restrict__ wp, int ldw,
                                        const float* xb, int xstride,
                                        int nkb, float4* acc) {
  float4 w0 = *(const float4*)(wp);
  float4 w1 = *(const float4*)(wp + ldw);
  float4 w2 = *(const float4*)(wp + 2 * (size_t)ldw);
  float4 w3 = *(const float4*)(wp + 3 * (size_t)ldw);
  for (int kb = 0; kb < nkb; ++kb) {
    float4 n0 = w0, n1 = w1, n2 = w2, n3 = w3;
    if (kb + 1 < nkb) {
      const float* wn = wp + (size_t)(kb + 1) * 4 * ldw;
      n0 = *(const float4*)(wn);
      n1 = *(const float4*)(wn + ldw);
      n2 = *(const float4*)(wn + 2 * (size_t)ldw);
      n3 = *(const float4*)(wn + 3 * (size_t)ldw);
    }
    const float* xp = xb + kb * 4;
    #pragma unroll
    for (int rr = 0; rr < 8; ++rr) {
      float4 xa = *(const float4*)(xp + rr * 4 * xstride);
      FMA16(acc[rr], xa, w0, w1, w2, w3)
    }
    w0 = n0; w1 = n1; w2 = n2; w3 = n3;
  }
}

__global__ __launch_bounds__(TPB, 4) void rnnt_fused(KArgs a) {
  const int tid  = threadIdx.x;
  const int bid  = blockIdx.x;
  const int lane = tid & 63;
  const int wv   = tid >> 6;      // wave 0..15
  const int cg   = lane & 15;     // colgroup (4 cols each)
  const int rg   = lane >> 4;     // rowgroup: rows rg + 4*rr

  __shared__ __align__(16) float s_X[2 * XHALF];   // 82,944 B
  __shared__ float s_acc[32 * 64];                 // 8 KB
  __shared__ unsigned long long s_red[64 * 17];    // 8.7 KB
  __shared__ int s_tok[NB];
  __shared__ unsigned char s_eq[NB], s_end[NB];

  for (int s = 0; s <= NSTEP; ++s) {
    const int p = s & 1;
    const float* nh_prev = p ? a.nh0 : a.nh1;
    const float* nc_prev = p ? a.nc0 : a.nc1;
    float* nh_cur = p ? a.nh1 : a.nh0;
    float* nc_cur = p ? a.nc1 : a.nc0;

    // ---------- finalize argmax of step s-1 (all WGs, redundant) ----------
    if (s > 0) {
      { int r = tid >> 4, m = tid & 15;
        const unsigned long long* pp = a.pmax + (size_t)r * 64 + m * 4;
        unsigned long long k0 = pp[0], k1 = pp[1], k2 = pp[2], k3 = pp[3];
        k0 = k0 > k1 ? k0 : k1; k2 = k2 > k3 ? k2 : k3;
        s_red[r * 17 + m] = k0 > k2 ? k0 : k2; }
      __syncthreads();
      if (tid < NB) {
        unsigned long long kk = 0;
        #pragma unroll
        for (int m = 0; m < 16; ++m) {
          unsigned long long v = s_red[tid * 17 + m];
          kk = v > kk ? v : kk;
        }
        int nt = (NV - 1) - (int)(kk & 0xFFFull);
        int eq = (nt == 0) ? 1 : 0;
        s_eq[tid] = (unsigned char)eq;
        if (!eq) s_tok[tid] = nt;
        int sym = (s - 1) % 3;
        unsigned char e = (sym == 0) ? (unsigned char)eq : (unsigned char)(s_end[tid] | eq);
        s_end[tid] = e;
        if (bid == 0) {
          int fr = (s - 1) / 3;
          int msk = (a.elen[tid] <= fr) || e;
          a.out[(size_t)tid * OUTW + s] = msk ? 0 : nt;
        }
      }
    } else {
      if (tid < NB) {
        s_tok[tid] = 0; s_eq[tid] = 1; s_end[tid] = 0;
        if (bid == 0) a.out[(size_t)tid * OUTW] = 0;
      }
    }
    __syncthreads();
    if (s == NSTEP) break;

    // =================== Interval 1 ===================
    if (bid < 80) {
      // gates = [emb|h] @ [Wx;Wh] : 32 rows x (4 gates x 16 j), K=1280 in 4 chunks
      const int cs = bid % 40, rh = bid / 40;     // partner WGs Δ=40 -> same XCD
      const int j0 = cs * 16;
      const int colg = (cg >> 2) * EH + j0 + (cg & 3) * 4;
      float4 acc[8];
      #pragma unroll
      for (int rr = 0; rr < 8; ++rr) acc[rr] = float4{0.f, 0.f, 0.f, 0.f};

      auto stage_g = [&](int c) {
        float* dst = s_X + (c & 1) * XHALF;
        for (int v = tid; v < 2560; v += TPB) {
          int r = v / 80, q = v - r * 80;
          int rowg = rh * 32 + r;
          const float* src;
          if (c < 2) {
            src = a.embed + (size_t)s_tok[rowg] * EH + c * 320 + q * 4;
          } else {
            const float* hp = s_eq[rowg] ? a.h_eff : nh_prev;
            src = hp + (size_t)rowg * EH + (c - 2) * 320 + q * 4;
          }
          *(float4*)(dst + r * XS_G + q * 4) = *(const float4*)src;
        }
      };
      for (int i = tid; i < 32 * 64; i += TPB) s_acc[i] = 0.0f;
      stage_g(0);
      __syncthreads();
      for (int c = 0; c < 4; ++c) {
        if (c < 3) stage_g(c + 1);
        const float* Wb = (c < 2) ? a.Wx + (size_t)(c * 320) * G4
                                  : a.Wh + (size_t)((c - 2) * 320) * G4;
        const float* wp = Wb + (size_t)(wv * 20) * G4 + colg;
        const float* xb = s_X + (c & 1) * XHALF + rg * XS_G + wv * 20;
        gemm_ks(wp, G4, xb, XS_G, 5, acc);
        __syncthreads();
      }
      #pragma unroll
      for (int rr = 0; rr < 8; ++rr) {
        float* d = &s_acc[(rg + 4 * rr) * 64 + cg * 4];
        atomicAdd(d + 0, acc[rr].x); atomicAdd(d + 1, acc[rr].y);
        atomicAdd(d + 2, acc[rr].z); atomicAdd(d + 3, acc[rr].w);
      }
      __syncthreads();
      if (tid < 512) {               // LSTM: 32 rows x 16 j
        const int r = tid >> 4, jl = tid & 15;
        const int rowg = rh * 32 + r, j = j0 + jl;
        float gi = s_acc[r * 64 +  0 + jl] + a.bl[j];
        float gf = s_acc[r * 64 + 16 + jl] + a.bl[EH + j];
        float gg = s_acc[r * 64 + 32 + jl] + a.bl[2 * EH + j];
        float go = s_acc[r * 64 + 48 + jl] + a.bl[3 * EH + j];
        float cp = s_eq[rowg] ? a.c_eff[(size_t)rowg * EH + j]
                              : nc_prev[(size_t)rowg * EH + j];
        float si = 1.0f / (1.0f + expf(-gi));
        float sf = 1.0f / (1.0f + expf(-gf));
        float so = 1.0f / (1.0f + expf(-go));
        float ncv = sf * cp + si * tanhf(gg);
        float nhv = so * tanhf(ncv);
        nh_cur[(size_t)rowg * EH + j] = nhv;
        nc_cur[(size_t)rowg * EH + j] = ncv;
      }
    } else if (bid < 100) {
      if (s % 3 == 0) {
        // encp = enc_t @ We : 32 rows x 64 cols, K=1024 in 4 chunks of 256
        const int eb = bid - 80;
        const int cs = eb % 10, rh = eb / 10;
        const int c0 = cs * 64, fr = s / 3;
        const int colg = c0 + cg * 4;
        float4 acc[8];
        #pragma unroll
        for (int rr = 0; rr < 8; ++rr) acc[rr] = float4{0.f, 0.f, 0.f, 0.f};
        auto stage_e = [&](int c) {
          float* dst = s_X + (c & 1) * XHALF;
          for (int v = tid; v < 2048; v += TPB) {
            int r = v >> 6, q = v & 63;
            int rowg = rh * 32 + r;
            const float* src = a.enc + ((size_t)rowg * NT + fr) * DE + c * 256 + q * 4;
            *(float4*)(dst + r * XS_E + q * 4) = *(const float4*)src;
          }
        };
        for (int i = tid; i < 32 * 64; i += TPB) s_acc[i] = 0.0f;
        stage_e(0);
        __syncthreads();
        for (int c = 0; c < 4; ++c) {
          if (c < 3) stage_e(c + 1);
          const float* wp = a.We + (size_t)(c * 256 + wv * 16) * EH + colg;
          const float* xb = s_X + (c & 1) * XHALF + rg * XS_E + wv * 16;
          gemm_ks(wp, EH, xb, XS_E, 4, acc);
          __syncthreads();
        }
        #pragma unroll
        for (int rr = 0; rr < 8; ++rr) {
          float* d = &s_acc[(rg + 4 * rr) * 64 + cg * 4];
          atomicAdd(d + 0, acc[rr].x); atomicAdd(d + 1, acc[rr].y);
          atomicAdd(d + 2, acc[rr].z); atomicAdd(d + 3, acc[rr].w);
        }
        __syncthreads();
        for (int v = tid; v < 2048; v += TPB) {
          int r = v >> 6, cl = v & 63;
          a.encp[(size_t)(rh * 32 + r) * EH + c0 + cl] = s_acc[v];
        }
      }
    } else if (bid < 104) {
      // lagged h/c writeback (rows with !eq; disjoint from gates' h_eff reads)
      const int base = (bid - 100) * 20480;
      #pragma unroll
      for (int i = 0; i < 20; ++i) {
        int e = base + i * TPB + tid;          // < 2*NB*EH = 81920
        int isC = e >= NB * EH;
        int e2 = isC ? e - NB * EH : e;
        int r = e2 / EH;
        if (!s_eq[r]) {
          if (isC) a.c_eff[e2] = nc_prev[e2];
          else     a.h_eff[e2] = nh_prev[e2];
        }
      }
    }
    gbar(a.bar, 3 * s + 1, bid);

    // =================== Interval 2 ===================
    if (bid < 20) {
      // jt = tanh(encp + nh @ Wd + bj) : 32 rows x 64 cols, K=640 flat
      const int cs = bid % 10, rh = bid / 10;
      const int c0 = cs * 64;
      const int colg = c0 + cg * 4;
      float4 acc[8];
      #pragma unroll
      for (int rr = 0; rr < 8; ++rr) acc[rr] = float4{0.f, 0.f, 0.f, 0.f};
      for (int i = tid; i < 32 * 64; i += TPB) s_acc[i] = 0.0f;
      for (int v = tid; v < 5120; v += TPB) {
        int r = v / 160, q = v - r * 160;
        const float* src = nh_cur + (size_t)(rh * 32 + r) * EH + q * 4;
        *(float4*)(s_X + r * XS_F + q * 4) = *(const float4*)src;
      }
      __syncthreads();
      {
        const float* wp = a.Wd + (size_t)(wv * 40) * EH + colg;
        const float* xb = s_X + rg * XS_F + wv * 40;
        gemm_ks(wp, EH, xb, XS_F, 10, acc);
      }
      #pragma unroll
      for (int rr = 0; rr < 8; ++rr) {
        float* d = &s_acc[(rg + 4 * rr) * 64 + cg * 4];
        atomicAdd(d + 0, acc[rr].x); atomicAdd(d + 1, acc[rr].y);
        atomicAdd(d + 2, acc[rr].z); atomicAdd(d + 3, acc[rr].w);
      }
      __syncthreads();
      for (int v = tid; v < 2048; v += TPB) {
        int r = v >> 6, cl = v & 63;
        int rowg = rh * 32 + r, col = c0 + cl;
        float jd = s_acc[v] + a.encp[(size_t)rowg * EH + col] + a.bj[col];
        a.jt[(size_t)rowg * EH + col] = tanhf(jd);
      }
    }
    gbar(a.bar, 3 * s + 2, bid);

    // =================== Interval 3 ===================
    {
      // logits = jt @ Wo + bo : 32 rows x 64 cols, K=640 flat; argmax partial
      const int cs = bid & 63, rh = bid >> 6;    // partner WGs Δ=64 -> same XCD
      const int c0 = cs * 64;
      const int colg = c0 + cg * 4;
      float4 acc[8];
      #pragma unroll
      for (int rr = 0; rr < 8; ++rr) acc[rr] = float4{0.f, 0.f, 0.f, 0.f};
      for (int i = tid; i < 32 * 64; i += TPB) s_acc[i] = 0.0f;
      for (int v = tid; v < 5120; v += TPB) {
        int r = v / 160, q = v - r * 160;
        const float* src = a.jt + (size_t)(rh * 32 + r) * EH + q * 4;
        *(float4*)(s_X + r * XS_F + q * 4) = *(const float4*)src;
      }
      __syncthreads();
      {
        const float* wp = a.Wo + (size_t)(wv * 40) * NV + colg;
        const float* xb = s_X + rg * XS_F + wv * 40;
        gemm_ks(wp, NV, xb, XS_F, 10, acc);
      }
      #pragma unroll
      for (int rr = 0; rr < 8; ++rr) {
        float* d = &s_acc[(rg + 4 * rr) * 64 + cg * 4];
        atomicAdd(d + 0, acc[rr].x); atomicAdd(d + 1, acc[rr].y);
        atomicAdd(d + 2, acc[rr].z); atomicAdd(d + 3, acc[rr].w);
      }
      __syncthreads();
      { int r = tid >> 5, m = tid & 31;
        int cA = 2 * m, cB = 2 * m + 1;
        float vA = s_acc[r * 64 + cA] + a.bo[c0 + cA];
        float vB = s_acc[r * 64 + cB] + a.bo[c0 + cB];
        unsigned long long kA =
            ((unsigned long long)fmono(vA) << 12) | (unsigned long long)(NV - 1 - (c0 + cA));
        unsigned long long kB =
            ((unsigned long long)fmono(vB) << 12) | (unsigned long long)(NV - 1 - (c0 + cB));
        s_red[r * 33 + m] = kA > kB ? kA : kB; }
      __syncthreads();
      if (tid < 32) {
        unsigned long long kk = 0;
        #pragma unroll
        for (int i = 0; i < 32; ++i) {
          unsigned long long v = s_red[tid * 33 + i];
          kk = v > kk ? v : kk;
        }
        a.pmax[(size_t)(rh * 32 + tid) * 64 + cs] = kk;
      }
    }
    gbar(a.bar, 3 * s + 3, bid);
  }
}

extern "C" void kernel_launch(void* const* d_in, const int* in_sizes, int n_in,
                              void* d_out, int out_size, void* d_ws, size_t ws_size,
                              hipStream_t stream) {
  KArgs a;
  a.enc   = (const float*)d_in[0];
  a.elen  = (const int*)  d_in[1];
  a.embed = (const float*)d_in[2];
  a.Wx    = (const float*)d_in[3];
  a.Wh    = (const float*)d_in[4];
  a.bl    = (const float*)d_in[5];
  a.We    = (const float*)d_in[6];
  a.Wd    = (const float*)d_in[7];
  a.bj    = (const float*)d_in[8];
  a.Wo    = (const float*)d_in[9];
  a.bo    = (const float*)d_in[10];
  a.out   = (int*)d_out;

  char* w = (char*)d_ws;
  size_t off = 0;
  auto alloc = [&](size_t bytes) -> char* {
    char* pp = w + off;
    off += (bytes + 255) & ~(size_t)255;
    return pp;
  };
  a.bar   = (int*)alloc(320 * 4);
  a.h_eff = (float*)alloc((size_t)NB * EH * 4);
  a.c_eff = (float*)alloc((size_t)NB * EH * 4);
  size_t zero_bytes = off;  // barrier + h_eff + c_eff must start at 0
  a.nh0  = (float*)alloc((size_t)NB * EH * 4);
  a.nh1  = (float*)alloc((size_t)NB * EH * 4);
  a.nc0  = (float*)alloc((size_t)NB * EH * 4);
  a.nc1  = (float*)alloc((size_t)NB * EH * 4);
  a.encp = (float*)alloc((size_t)NB * EH * 4);
  a.jt   = (float*)alloc((size_t)NB * EH * 4);
  a.pmax = (unsigned long long*)alloc((size_t)NB * 64 * 8);

  hipMemsetAsync(d_ws, 0, zero_bytes, stream);
  void* params[] = { &a };
  hipLaunchCooperativeKernel((const void*)rnnt_fused, dim3(NWG), dim3(TPB),
                             params, 0, stream);
}